// Round 1
// baseline (312.126 us; speedup 1.0000x reference)
//
#include <hip/hip_runtime.h>

// DeformConvBlock B=4,C=64,H=W=256,OUT=64 — fp16 MFMA pipeline.
// R7: latency attack. deform_main was 6% Mfma / 15% VALU / 44% occ — pure
// memory-latency bound with ~1 serialized gather round-trip per tap
// (#pragma unroll 1 pinned it). Changes:
//  * full unroll of both tap loops (VGPR 52 -> cap 128, scheduler hoists
//    next taps' gathers over current blend/MFMA)
//  * branchless phase-1 row guard (no CF in the unrolled body)
//  * ds_read_b64 paired offset reads
//  * nontemporal out stores (64MB stream was thrashing the 4MB/XCD L2
//    that holds the gather working set)
//  * transpose rewritten LDS-free: 1 px/thread, 64 coalesced dword reads
//    in flight, pack f16 in regs, 8x16B contiguous stores; weight prep is
//    now coalesced-read + scatter-STORE (fire-and-forget) instead of
//    serialized scattered loads.

typedef _Float16 half8 __attribute__((ext_vector_type(8)));
typedef _Float16 h2    __attribute__((ext_vector_type(2)));
typedef float floatx4  __attribute__((ext_vector_type(4)));

namespace {
constexpr int B_ = 4, C_ = 64, H_ = 256, W_ = 256, OUT_ = 64;
constexpr int HW_ = H_ * W_;
constexpr size_t XT_BYTES = (size_t)B_ * HW_ * C_ * 2;      // 32 MB NHWC f16
constexpr size_t WOFF_OFF = XT_BYTES;                        // [9][2][2][64][8] f16
constexpr int    WOFF_N   = 9 * 2 * 2 * 64 * 8;
constexpr size_t WDEF_OFF = WOFF_OFF + (size_t)WOFF_N * 2;   // [9][2][4][64][8] f16
constexpr int    WDEF_N   = 9 * 2 * 4 * 64 * 8;
}

// ------- K1: x CHW f32 -> NHWC f16 (+ weight prep in first 32 blocks) -------
// One block per (b,y) row. Thread t owns pixel px=t: 64 independent
// coalesced dword reads (per wave instr: 64 consecutive floats = 256B),
// convert+pack in regs, 8 contiguous 16B stores. No LDS, no barrier.
__global__ __launch_bounds__(256)
void transpose_x(const float* __restrict__ x, _Float16* __restrict__ xt,
                 const float* __restrict__ w_off, const float* __restrict__ w_def,
                 _Float16* __restrict__ wof, _Float16* __restrict__ wdf)
{
    const int bid = blockIdx.x;            // b*256 + y
    const int b = bid >> 8, y = bid & 255;
    const int px = threadIdx.x;
    const float* __restrict__ xp = x + (size_t)b * C_ * HW_ + y * W_ + px;

    union { _Float16 h[64]; uint4 u[8]; } v;
#pragma unroll
    for (int c = 0; c < C_; ++c) v.h[c] = (_Float16)xp[(size_t)c * HW_];

    uint4* __restrict__ dst = (uint4*)(xt + ((size_t)bid * W_ + px) * C_);
#pragma unroll
    for (int k = 0; k < 8; ++k) dst[k] = v.u[k];

    // ---- weight prep (blocks 0..31): coalesced reads, scattered stores ----
    if (bid < 32) {
        const int i0 = bid * 256 + threadIdx.x;          // 0..8191
        for (int s = i0; s < OUT_ * C_ * 9; s += 8192) {  // wdf: 36864 elems
            const int n = s / 576;                        // 576 = 64*9
            const int r = s - n * 576;
            const int c = r / 9;
            const int tap = r - c * 9;
            const int idx = ((((tap * 2 + (c >> 5)) * 4 + (n >> 4)) * 64
                              + ((c >> 3) & 3) * 16 + (n & 15)) << 3) + (c & 7);
            wdf[idx] = (_Float16)w_def[s];
        }
        for (int s = i0; s < 18 * C_ * 9; s += 8192) {    // wof: 10368 elems
            const int n = s / 576;
            const int r = s - n * 576;
            const int c = r / 9;
            const int tap = r - c * 9;
            const int idx = ((((tap * 2 + (c >> 5)) * 2 + (n >> 4)) * 64
                              + ((c >> 3) & 3) * 16 + (n & 15)) << 3) + (c & 7);
            wof[idx] = (_Float16)w_off[s];
        }
        // zero padding slots (n = 16 + (lane&15) >= 18); disjoint from above
        for (int i = i0; i < WOFF_N; i += 8192) {
            const int lane = (i >> 3) & 63, nt = (i >> 9) & 1;
            if (nt == 1 && (lane & 15) >= 2) wof[i] = (_Float16)0.0f;
        }
    }
}

// ---------------- K2 helpers ----------------
__device__ __forceinline__ void bilin_setup(float ys, float xs, int* a, float* w)
{
    const float y0f = floorf(ys), x0f = floorf(xs);
    const float ly = ys - y0f, lx = xs - x0f;
    const int y0 = (int)y0f, x0 = (int)x0f;
    const int y1 = y0 + 1, x1 = x0 + 1;
    const int y0c = min(max(y0, 0), H_ - 1);
    const int y1c = min(max(y1, 0), H_ - 1);
    const int x0c = min(max(x0, 0), W_ - 1);
    const int x1c = min(max(x1, 0), W_ - 1);
    const float fy0 = (y0 >= 0 && y0 < H_) ? 1.0f : 0.0f;
    const float fy1 = (y1 >= 0 && y1 < H_) ? 1.0f : 0.0f;
    const float fx0 = (x0 >= 0 && x0 < W_) ? 1.0f : 0.0f;
    const float fx1 = (x1 >= 0 && x1 < W_) ? 1.0f : 0.0f;
    a[0] = y0c * W_ + x0c;  w[0] = (1.0f - ly) * (1.0f - lx) * fy0 * fx0;
    a[1] = y0c * W_ + x1c;  w[1] = (1.0f - ly) * lx          * fy0 * fx1;
    a[2] = y1c * W_ + x0c;  w[2] = ly          * (1.0f - lx) * fy1 * fx0;
    a[3] = y1c * W_ + x1c;  w[3] = ly          * lx          * fy1 * fx1;
}

// ---------------- K2: fused deform conv (f16 MFMA) ----------------
__global__ __launch_bounds__(256, 4)
void deform_main(const _Float16* __restrict__ xt,
                 const _Float16* __restrict__ wof,
                 const float* __restrict__ b_off,
                 const _Float16* __restrict__ wdf,
                 const float* __restrict__ b_def,
                 float* __restrict__ out)
{
    __shared__ float off_lds[128 * 18];       // per-pixel offsets (this half-row)

    const int tid = threadIdx.x;
    const int lane = tid & 63;
    const int wv = tid >> 6;            // wave id: local px [wv*32, wv*32+32)
    const int lm = lane & 15;
    const int lq = lane >> 4;
    const int bid = blockIdx.x;                      // 2048
    const int uid = (bid & 7) * 256 + (bid >> 3);    // XCD band swizzle
    const int row = uid >> 1, half = uid & 1;
    const int b = row >> 8, y = row & 255;
    const int base = half * 128;                     // px window [base, base+128)
    const _Float16* __restrict__ xtb = xt + (size_t)b * HW_ * C_;

    // ================= phase 1: offsets via MFMA =================
    {
        floatx4 acc1[2][2];
#pragma unroll
        for (int pt = 0; pt < 2; ++pt)
#pragma unroll
            for (int nt = 0; nt < 2; ++nt) acc1[pt][nt] = (floatx4)0.0f;

#pragma unroll
        for (int tap = 0; tap < 9; ++tap) {
            const int dy = tap / 3 - 1, dx = tap % 3 - 1;
            const int ys = y + dy;
            const bool yok = (unsigned)ys < 256u;
            const int ysc = min(max(ys, 0), 255);
#pragma unroll
            for (int kc = 0; kc < 2; ++kc) {
                half8 bfr[2];
#pragma unroll
                for (int nt = 0; nt < 2; ++nt)
                    bfr[nt] = *(const half8*)(wof +
                        ((size_t)(((tap * 2 + kc) * 2 + nt) * 64 + lane)) * 8);
#pragma unroll
                for (int pt = 0; pt < 2; ++pt) {
                    const int px_s = base + wv * 32 + pt * 16 + lm + dx;
                    const bool vld = yok && ((unsigned)px_s < 256u);
                    const int pxc = min(max(px_s, 0), 255);
                    uint4 t = *(const uint4*)(xtb +
                        ((size_t)ysc * 256 + pxc) * 64 + kc * 32 + lq * 8);
                    if (!vld) { t.x = 0u; t.y = 0u; t.z = 0u; t.w = 0u; }
                    const half8 afr = __builtin_bit_cast(half8, t);
#pragma unroll
                    for (int nt = 0; nt < 2; ++nt)
                        acc1[pt][nt] = __builtin_amdgcn_mfma_f32_16x16x32_f16(
                            afr, bfr[nt], acc1[pt][nt], 0, 0, 0);
                }
            }
        }
#pragma unroll
        for (int nt = 0; nt < 2; ++nt) {
            const int j = nt * 16 + lm;
            if (j < 18) {
                const float bj = b_off[j];
#pragma unroll
                for (int pt = 0; pt < 2; ++pt) {
#pragma unroll
                    for (int r = 0; r < 4; ++r) {
                        const int lpx = wv * 32 + pt * 16 + lq * 4 + r;
                        off_lds[lpx * 18 + j] = acc1[pt][nt][r] + bj;
                    }
                }
            }
        }
    }
    __syncthreads();   // the ONLY barrier

    // ================= phase 2: per-thread f16 A-frag gather + MFMA =========
    floatx4 acc[2][4];
#pragma unroll
    for (int pt = 0; pt < 2; ++pt)
#pragma unroll
        for (int ot = 0; ot < 4; ++ot) acc[pt][ot] = (floatx4)0.0f;

#pragma unroll
    for (int tap = 0; tap < 9; ++tap) {
        const int ki = tap / 3, kj = tap % 3;
        int ca[2][4];
        h2 cw[2][4];
#pragma unroll
        for (int pt = 0; pt < 2; ++pt) {
            const int lpx = wv * 32 + pt * 16 + lm;
            const float2 o2 = *(const float2*)&off_lds[lpx * 18 + tap * 2];
            const float ys = (float)(y + ki - 1) + o2.x;
            const float xs = (float)(base + lpx + kj - 1) + o2.y;
            float cwf[4];
            bilin_setup(ys, xs, ca[pt], cwf);
#pragma unroll
            for (int c = 0; c < 4; ++c) cw[pt][c] = (h2)((_Float16)cwf[c]);
        }

#pragma unroll
        for (int kc = 0; kc < 2; ++kc) {
            half8 bfr[4];
#pragma unroll
            for (int ot = 0; ot < 4; ++ot)
                bfr[ot] = *(const half8*)(wdf +
                    ((size_t)(((tap * 2 + kc) * 4 + ot) * 64 + lane)) * 8);

            const int sub = kc * 32 + lq * 8;
#pragma unroll
            for (int pt = 0; pt < 2; ++pt) {
                union Uc { uint4 u; h2 p[4]; } c0, c1, c2, c3;
                c0.u = *(const uint4*)(xtb + (size_t)ca[pt][0] * 64 + sub);
                c1.u = *(const uint4*)(xtb + (size_t)ca[pt][1] * 64 + sub);
                c2.u = *(const uint4*)(xtb + (size_t)ca[pt][2] * 64 + sub);
                c3.u = *(const uint4*)(xtb + (size_t)ca[pt][3] * 64 + sub);
                union Rr { h2 s[4]; half8 v; } r;
#pragma unroll
                for (int k = 0; k < 4; ++k)
                    r.s[k] = cw[pt][0] * c0.p[k] + cw[pt][1] * c1.p[k]
                           + cw[pt][2] * c2.p[k] + cw[pt][3] * c3.p[k];
#pragma unroll
                for (int ot = 0; ot < 4; ++ot)
                    acc[pt][ot] = __builtin_amdgcn_mfma_f32_16x16x32_f16(
                        r.v, bfr[ot], acc[pt][ot], 0, 0, 0);
            }
        }
    }

    // ================= epilogue: nontemporal float4 stores =================
#pragma unroll
    for (int ot = 0; ot < 4; ++ot) {
        const int o = ot * 16 + lm;
        const float bd = b_def[o];
#pragma unroll
        for (int pt = 0; pt < 2; ++pt) {
            const int pxs = base + wv * 32 + pt * 16 + lq * 4;
            floatx4 a = acc[pt][ot];
            a[0] += bd; a[1] += bd; a[2] += bd; a[3] += bd;
            __builtin_nontemporal_store(a,
                (floatx4*)&out[(((size_t)b * OUT_ + o) * H_ + y) * W_ + pxs]);
        }
    }
}

extern "C" void kernel_launch(void* const* d_in, const int* in_sizes, int n_in,
                              void* d_out, int out_size, void* d_ws, size_t ws_size,
                              hipStream_t stream)
{
    const float* x     = (const float*)d_in[0];
    const float* w_off = (const float*)d_in[1];
    const float* b_off = (const float*)d_in[2];
    const float* w_def = (const float*)d_in[3];
    const float* b_def = (const float*)d_in[4];
    float* out = (float*)d_out;

    _Float16* xt  = (_Float16*)d_ws;
    _Float16* wof = (_Float16*)((char*)d_ws + WOFF_OFF);
    _Float16* wdf = (_Float16*)((char*)d_ws + WDEF_OFF);

    transpose_x<<<dim3(B_ * H_), dim3(256), 0, stream>>>(
        x, xt, w_off, w_def, wof, wdf);
    deform_main<<<dim3(B_ * H_ * 2), dim3(256), 0, stream>>>(
        xt, wof, b_off, wdf, b_def, out);
}

// Round 2
// 232.224 us; speedup vs baseline: 1.3441x; 1.3441x over previous
//
#include <hip/hip_runtime.h>

// DeformConvBlock B=4,C=64,H=W=256,OUT=64 — fp16 MFMA pipeline.
// R8: address-throughput attack. R7 showed unroll changed nothing (TA/request
// bound, not schedule bound): xt's [px][64ch] layout guarantees 128B lane
// stride in every gather -> 64 uncoalesced requests/instr, every corner a
// distinct 64B line. Changes:
//  * xt re-layout to plane-major [y][kcq=ch/8][px][8ch(16B)]: quad lanes now
//    read pixel-stride-16B granules (offsets are small -> usually contiguous
//    -> quad-coalesce); corner x0/x0+1 land 16B apart (L1 hit) instead of
//    128B (always a new line). Value->lane mapping unchanged; MFMA frags
//    identical, only addresses change.
//  * 2D blocks: 4 waves = 4 consecutive rows x one 32-px window (shared L1
//    gather window ~38KB vs ~84KB).
//  * K1 stores now fully contiguous 1KB/instr (was 64 partial lines/instr).
//  * NT stores reverted (R7: WRITE_SIZE 65.5->113.7MB regression).

typedef _Float16 half8 __attribute__((ext_vector_type(8)));
typedef _Float16 h2    __attribute__((ext_vector_type(2)));
typedef float floatx4  __attribute__((ext_vector_type(4)));

namespace {
constexpr int B_ = 4, C_ = 64, H_ = 256, W_ = 256, OUT_ = 64;
constexpr int HW_ = H_ * W_;
constexpr size_t XT_BYTES = (size_t)B_ * HW_ * C_ * 2;      // 32 MB plane-major f16
constexpr size_t WOFF_OFF = XT_BYTES;                        // [9][2][2][64][8] f16
constexpr int    WOFF_N   = 9 * 2 * 2 * 64 * 8;
constexpr size_t WDEF_OFF = WOFF_OFF + (size_t)WOFF_N * 2;   // [9][2][4][64][8] f16
constexpr int    WDEF_N   = 9 * 2 * 4 * 64 * 8;
// xt granule index: (((b*256 + y)*8 + kcq)*256 + px), each granule = 8 f16 = 16B
}

// ------- K1: x CHW f32 -> plane-major f16 (+ weight prep in first 32 blocks) -
// One block per (b,y) row. Thread t owns pixel px=t: 64 coalesced dword reads,
// pack to f16 in regs, store 8 granules at plane stride (each store instr:
// 64 lanes x 16B consecutive px = 1KB fully contiguous).
__global__ __launch_bounds__(256)
void transpose_x(const float* __restrict__ x, _Float16* __restrict__ xt,
                 const float* __restrict__ w_off, const float* __restrict__ w_def,
                 _Float16* __restrict__ wof, _Float16* __restrict__ wdf)
{
    const int bid = blockIdx.x;            // b*256 + y
    const int b = bid >> 8, y = bid & 255;
    const int px = threadIdx.x;
    const float* __restrict__ xp = x + (size_t)b * C_ * HW_ + y * W_ + px;

    union { _Float16 h[64]; uint4 u[8]; } v;
#pragma unroll
    for (int c = 0; c < C_; ++c) v.h[c] = (_Float16)xp[(size_t)c * HW_];

    // granule (bid*8 + k)*256 + px, elem offset x8
    _Float16* __restrict__ d0 = xt + ((size_t)(bid * 8) * 256 + px) * 8;
#pragma unroll
    for (int k = 0; k < 8; ++k)
        *(uint4*)(d0 + (size_t)k * 256 * 8) = v.u[k];

    // ---- weight prep (blocks 0..31): coalesced reads, scattered stores ----
    if (bid < 32) {
        const int i0 = bid * 256 + threadIdx.x;          // 0..8191
        for (int s = i0; s < OUT_ * C_ * 9; s += 8192) {  // wdf: 36864 elems
            const int n = s / 576;                        // 576 = 64*9
            const int r = s - n * 576;
            const int c = r / 9;
            const int tap = r - c * 9;
            const int idx = ((((tap * 2 + (c >> 5)) * 4 + (n >> 4)) * 64
                              + ((c >> 3) & 3) * 16 + (n & 15)) << 3) + (c & 7);
            wdf[idx] = (_Float16)w_def[s];
        }
        for (int s = i0; s < 18 * C_ * 9; s += 8192) {    // wof: 10368 elems
            const int n = s / 576;
            const int r = s - n * 576;
            const int c = r / 9;
            const int tap = r - c * 9;
            const int idx = ((((tap * 2 + (c >> 5)) * 2 + (n >> 4)) * 64
                              + ((c >> 3) & 3) * 16 + (n & 15)) << 3) + (c & 7);
            wof[idx] = (_Float16)w_off[s];
        }
        // zero padding slots (n = 16 + (lane&15) >= 18); disjoint from above
        for (int i = i0; i < WOFF_N; i += 8192) {
            const int lane = (i >> 3) & 63, nt = (i >> 9) & 1;
            if (nt == 1 && (lane & 15) >= 2) wof[i] = (_Float16)0.0f;
        }
    }
}

// ---------------- K2 helpers ----------------
// a[i] = granule base (yc*2048 + xc); add (kc*4+lq)*256 for the channel plane.
__device__ __forceinline__ void bilin_setup(float ys, float xs, int* a, float* w)
{
    const float y0f = floorf(ys), x0f = floorf(xs);
    const float ly = ys - y0f, lx = xs - x0f;
    const int y0 = (int)y0f, x0 = (int)x0f;
    const int y1 = y0 + 1, x1 = x0 + 1;
    const int y0c = min(max(y0, 0), H_ - 1);
    const int y1c = min(max(y1, 0), H_ - 1);
    const int x0c = min(max(x0, 0), W_ - 1);
    const int x1c = min(max(x1, 0), W_ - 1);
    const float fy0 = (y0 >= 0 && y0 < H_) ? 1.0f : 0.0f;
    const float fy1 = (y1 >= 0 && y1 < H_) ? 1.0f : 0.0f;
    const float fx0 = (x0 >= 0 && x0 < W_) ? 1.0f : 0.0f;
    const float fx1 = (x1 >= 0 && x1 < W_) ? 1.0f : 0.0f;
    a[0] = y0c * 2048 + x0c;  w[0] = (1.0f - ly) * (1.0f - lx) * fy0 * fx0;
    a[1] = y0c * 2048 + x1c;  w[1] = (1.0f - ly) * lx          * fy0 * fx1;
    a[2] = y1c * 2048 + x0c;  w[2] = ly          * (1.0f - lx) * fy1 * fx0;
    a[3] = y1c * 2048 + x1c;  w[3] = ly          * lx          * fy1 * fx1;
}

// ---------------- K2: fused deform conv (f16 MFMA) ----------------
__global__ __launch_bounds__(256, 4)
void deform_main(const _Float16* __restrict__ xt,
                 const _Float16* __restrict__ wof,
                 const float* __restrict__ b_off,
                 const _Float16* __restrict__ wdf,
                 const float* __restrict__ b_def,
                 float* __restrict__ out)
{
    __shared__ float off_lds[128 * 18];       // per-pixel offsets (4 rows x 32 px)

    const int tid = threadIdx.x;
    const int lane = tid & 63;
    const int wv = tid >> 6;            // wave id: row y0+wv
    const int lm = lane & 15;
    const int lq = lane >> 4;
    const int bid = blockIdx.x;                      // 2048
    const int uid = (bid & 7) * 256 + (bid >> 3);    // XCD band swizzle
    const int colc = uid & 7;
    const int rowg = (uid >> 3) & 63;
    const int b = uid >> 9;
    const int y0 = rowg * 4;
    const int y = y0 + wv;                           // this wave's row
    const int base = colc * 32;                      // px window [base, base+32)
    const _Float16* __restrict__ xtb = xt + (size_t)b * HW_ * C_;

    // ================= phase 1: offsets via MFMA =================
    {
        floatx4 acc1[2][2];
#pragma unroll
        for (int pt = 0; pt < 2; ++pt)
#pragma unroll
            for (int nt = 0; nt < 2; ++nt) acc1[pt][nt] = (floatx4)0.0f;

#pragma unroll
        for (int tap = 0; tap < 9; ++tap) {
            const int dy = tap / 3 - 1, dx = tap % 3 - 1;
            const int ys = y + dy;
            const bool yok = (unsigned)ys < 256u;
            const int ysc = min(max(ys, 0), 255);
#pragma unroll
            for (int kc = 0; kc < 2; ++kc) {
                half8 bfr[2];
#pragma unroll
                for (int nt = 0; nt < 2; ++nt)
                    bfr[nt] = *(const half8*)(wof +
                        ((size_t)(((tap * 2 + kc) * 2 + nt) * 64 + lane)) * 8);
                const int plane = (kc * 4 + lq) * 256;
#pragma unroll
                for (int pt = 0; pt < 2; ++pt) {
                    const int px_s = base + pt * 16 + lm + dx;
                    const bool vld = yok && ((unsigned)px_s < 256u);
                    const int pxc = min(max(px_s, 0), 255);
                    uint4 t = *(const uint4*)(xtb +
                        ((size_t)(ysc * 2048 + plane + pxc)) * 8);
                    if (!vld) { t.x = 0u; t.y = 0u; t.z = 0u; t.w = 0u; }
                    const half8 afr = __builtin_bit_cast(half8, t);
#pragma unroll
                    for (int nt = 0; nt < 2; ++nt)
                        acc1[pt][nt] = __builtin_amdgcn_mfma_f32_16x16x32_f16(
                            afr, bfr[nt], acc1[pt][nt], 0, 0, 0);
                }
            }
        }
#pragma unroll
        for (int nt = 0; nt < 2; ++nt) {
            const int j = nt * 16 + lm;
            if (j < 18) {
                const float bj = b_off[j];
#pragma unroll
                for (int pt = 0; pt < 2; ++pt) {
#pragma unroll
                    for (int r = 0; r < 4; ++r) {
                        const int lpx = wv * 32 + pt * 16 + lq * 4 + r;
                        off_lds[lpx * 18 + j] = acc1[pt][nt][r] + bj;
                    }
                }
            }
        }
    }
    __syncthreads();   // the ONLY barrier

    // ================= phase 2: per-thread f16 A-frag gather + MFMA =========
    floatx4 acc[2][4];
#pragma unroll
    for (int pt = 0; pt < 2; ++pt)
#pragma unroll
        for (int ot = 0; ot < 4; ++ot) acc[pt][ot] = (floatx4)0.0f;

#pragma unroll
    for (int tap = 0; tap < 9; ++tap) {
        const int ki = tap / 3, kj = tap % 3;
        int ca[2][4];
        h2 cw[2][4];
#pragma unroll
        for (int pt = 0; pt < 2; ++pt) {
            const int lpx = wv * 32 + pt * 16 + lm;
            const float2 o2 = *(const float2*)&off_lds[lpx * 18 + tap * 2];
            const float ys = (float)(y + ki - 1) + o2.x;
            const float xs = (float)(base + pt * 16 + lm + kj - 1) + o2.y;
            float cwf[4];
            bilin_setup(ys, xs, ca[pt], cwf);
#pragma unroll
            for (int c = 0; c < 4; ++c) cw[pt][c] = (h2)((_Float16)cwf[c]);
        }

#pragma unroll
        for (int kc = 0; kc < 2; ++kc) {
            half8 bfr[4];
#pragma unroll
            for (int ot = 0; ot < 4; ++ot)
                bfr[ot] = *(const half8*)(wdf +
                    ((size_t)(((tap * 2 + kc) * 4 + ot) * 64 + lane)) * 8);

            const int plane = (kc * 4 + lq) * 256;
#pragma unroll
            for (int pt = 0; pt < 2; ++pt) {
                union Uc { uint4 u; h2 p[4]; } c0, c1, c2, c3;
                c0.u = *(const uint4*)(xtb + (size_t)(ca[pt][0] + plane) * 8);
                c1.u = *(const uint4*)(xtb + (size_t)(ca[pt][1] + plane) * 8);
                c2.u = *(const uint4*)(xtb + (size_t)(ca[pt][2] + plane) * 8);
                c3.u = *(const uint4*)(xtb + (size_t)(ca[pt][3] + plane) * 8);
                union Rr { h2 s[4]; half8 v; } r;
#pragma unroll
                for (int k = 0; k < 4; ++k)
                    r.s[k] = cw[pt][0] * c0.p[k] + cw[pt][1] * c1.p[k]
                           + cw[pt][2] * c2.p[k] + cw[pt][3] * c3.p[k];
#pragma unroll
                for (int ot = 0; ot < 4; ++ot)
                    acc[pt][ot] = __builtin_amdgcn_mfma_f32_16x16x32_f16(
                        r.v, bfr[ot], acc[pt][ot], 0, 0, 0);
            }
        }
    }

    // ================= epilogue: float4 stores =================
#pragma unroll
    for (int ot = 0; ot < 4; ++ot) {
        const int o = ot * 16 + lm;
        const float bd = b_def[o];
#pragma unroll
        for (int pt = 0; pt < 2; ++pt) {
            const int pxs = base + pt * 16 + lq * 4;
            const floatx4 a = acc[pt][ot];
            float4 v = make_float4(a[0] + bd, a[1] + bd, a[2] + bd, a[3] + bd);
            *(float4*)&out[(((size_t)b * OUT_ + o) * H_ + y) * W_ + pxs] = v;
        }
    }
}

extern "C" void kernel_launch(void* const* d_in, const int* in_sizes, int n_in,
                              void* d_out, int out_size, void* d_ws, size_t ws_size,
                              hipStream_t stream)
{
    const float* x     = (const float*)d_in[0];
    const float* w_off = (const float*)d_in[1];
    const float* b_off = (const float*)d_in[2];
    const float* w_def = (const float*)d_in[3];
    const float* b_def = (const float*)d_in[4];
    float* out = (float*)d_out;

    _Float16* xt  = (_Float16*)d_ws;
    _Float16* wof = (_Float16*)((char*)d_ws + WOFF_OFF);
    _Float16* wdf = (_Float16*)((char*)d_ws + WDEF_OFF);

    transpose_x<<<dim3(B_ * H_), dim3(256), 0, stream>>>(
        x, xt, w_off, w_def, wof, wdf);
    deform_main<<<dim3(B_ * H_ * 2), dim3(256), 0, stream>>>(
        xt, wof, b_off, wdf, b_def, out);
}